// Round 1
// baseline (79.977 us; speedup 1.0000x reference)
//
#include <hip/hip_runtime.h>

// Problem constants (from reference):
// B=8, C=5, D=4 -> Ch=20 -> planes = B*Ch = 160
// H=W=512, K=2, STRIDE=2 -> Hout=Wout=256
// DEVALUE = 1/(2*2) = 0.25
#define NPLANES 160
#define HIN 512
#define WIN 512
#define HOUT 256
#define WOUT 256
#define DEVALUE 0.25f

// One thread handles 2 adjacent output pixels (one float4-wide strip of input).
__global__ __launch_bounds__(256) void pool_gather_kernel(
    const float* __restrict__ e,
    const float* __restrict__ ce,
    float* __restrict__ out_e,
    float* __restrict__ out_ce)
{
    const int W2 = WOUT / 2;  // 128 thread-columns per output row
    int t = blockIdx.x * blockDim.x + threadIdx.x;

    int wo2 = t % W2;
    int tmp = t / W2;
    int ho  = tmp % HOUT;
    int bc  = tmp / HOUT;
    if (bc >= NPLANES) return;

    // Input window top-left for the two windows this thread owns.
    size_t in_base = (size_t)bc * (HIN * WIN) + (size_t)(ho * 2) * WIN + (size_t)(wo2 * 4);

    const float4 e0 = *reinterpret_cast<const float4*>(e  + in_base);        // row 0, e
    const float4 e1 = *reinterpret_cast<const float4*>(e  + in_base + WIN);  // row 1, e
    const float4 c0 = *reinterpret_cast<const float4*>(ce + in_base);        // row 0, ce
    const float4 c1 = *reinterpret_cast<const float4*>(ce + in_base + WIN);  // row 1, ce

    float2 eo, co;

    // Window 0: columns {x, y} of rows 0/1.
    {
        float v0 = c0.x * (1.0f - e0.x);  // window idx 0 (r0,c0)
        float v1 = c0.y * (1.0f - e0.y);  // window idx 1 (r0,c1)
        float v2 = c1.x * (1.0f - e1.x);  // window idx 2 (r1,c0)
        float v3 = c1.y * (1.0f - e1.y);  // window idx 3 (r1,c1)
        float best = v0, es = e0.x, cs = c0.x;
        if (v1 > best) { best = v1; es = e0.y; cs = c0.y; }
        if (v2 > best) { best = v2; es = e1.x; cs = c1.x; }
        if (v3 > best) { best = v3; es = e1.y; cs = c1.y; }
        eo.x = es;
        co.x = DEVALUE * cs;
    }

    // Window 1: columns {z, w} of rows 0/1.
    {
        float v0 = c0.z * (1.0f - e0.z);
        float v1 = c0.w * (1.0f - e0.w);
        float v2 = c1.z * (1.0f - e1.z);
        float v3 = c1.w * (1.0f - e1.w);
        float best = v0, es = e0.z, cs = c0.z;
        if (v1 > best) { best = v1; es = e0.w; cs = c0.w; }
        if (v2 > best) { best = v2; es = e1.z; cs = c1.z; }
        if (v3 > best) { best = v3; es = e1.w; cs = c1.w; }
        eo.y = es;
        co.y = DEVALUE * cs;
    }

    size_t out_base = (size_t)bc * (HOUT * WOUT) + (size_t)ho * WOUT + (size_t)(wo2 * 2);
    *reinterpret_cast<float2*>(out_e  + out_base) = eo;
    *reinterpret_cast<float2*>(out_ce + out_base) = co;
}

extern "C" void kernel_launch(void* const* d_in, const int* in_sizes, int n_in,
                              void* d_out, int out_size, void* d_ws, size_t ws_size,
                              hipStream_t stream) {
    // Inputs (setup_inputs order): d [unused], cd [unused], e, ce
    const float* e  = (const float*)d_in[2];
    const float* ce = (const float*)d_in[3];

    const size_t plane_out = (size_t)NPLANES * HOUT * WOUT;  // 10,485,760
    float* out_e  = (float*)d_out;
    float* out_ce = out_e + plane_out;

    const long long total_threads = (long long)NPLANES * HOUT * (WOUT / 2);  // 5,242,880
    const int block = 256;
    const long long grid = (total_threads + block - 1) / block;  // 20480

    pool_gather_kernel<<<(dim3)(unsigned)grid, block, 0, stream>>>(e, ce, out_e, out_ce);
}

// Round 4
// 74.358 us; speedup vs baseline: 1.0756x; 1.0756x over previous
//
#include <hip/hip_runtime.h>

// B=8, C=5, D=4 -> planes = 160; H=W=512 -> Hout=Wout=256; K=STRIDE=2; DEVALUE=0.25
#define NPLANES 160
#define HIN 512
#define WIN 512
#define HOUT 256
#define WOUT 256
#define DEVALUE 0.25f

typedef float floatx4 __attribute__((ext_vector_type(4)));

// argmax over one 2x2 window (first-max tie-break order: (r0,c0),(r0,c1),(r1,c0),(r1,c1))
__device__ __forceinline__ void win2x2(float e00, float e01, float e10, float e11,
                                       float c00, float c01, float c10, float c11,
                                       float& eo, float& co)
{
    float v0 = c00 * (1.0f - e00);
    float v1 = c01 * (1.0f - e01);
    float v2 = c10 * (1.0f - e10);
    float v3 = c11 * (1.0f - e11);
    float best = v0; eo = e00; co = c00;
    if (v1 > best) { best = v1; eo = e01; co = c01; }
    if (v2 > best) { best = v2; eo = e10; co = c10; }
    if (v3 > best) { best = v3; eo = e11; co = c11; }
}

// One thread handles 4 adjacent output pixels (8 input columns x 2 rows).
__global__ __launch_bounds__(256) void pool_gather_kernel(
    const float* __restrict__ e,
    const float* __restrict__ ce,
    float* __restrict__ out_e,
    float* __restrict__ out_ce)
{
    int t = blockIdx.x * 256 + threadIdx.x;
    int wo4 = t & 63;          // 64 thread-columns per output row (4 pixels each)
    int ho  = (t >> 6) & 255;  // output row
    int bc  = t >> 14;         // plane

    size_t in_base = (size_t)bc * (HIN * WIN) + (size_t)(ho * 2) * WIN + (size_t)(wo4 * 8);

    const float4 e0a = *reinterpret_cast<const float4*>(e  + in_base);
    const float4 e0b = *reinterpret_cast<const float4*>(e  + in_base + 4);
    const float4 e1a = *reinterpret_cast<const float4*>(e  + in_base + WIN);
    const float4 e1b = *reinterpret_cast<const float4*>(e  + in_base + WIN + 4);
    const float4 c0a = *reinterpret_cast<const float4*>(ce + in_base);
    const float4 c0b = *reinterpret_cast<const float4*>(ce + in_base + 4);
    const float4 c1a = *reinterpret_cast<const float4*>(ce + in_base + WIN);
    const float4 c1b = *reinterpret_cast<const float4*>(ce + in_base + WIN + 4);

    float e0o, c0o, e1o, c1o, e2o, c2o, e3o, c3o;
    win2x2(e0a.x, e0a.y, e1a.x, e1a.y,  c0a.x, c0a.y, c1a.x, c1a.y,  e0o, c0o);
    win2x2(e0a.z, e0a.w, e1a.z, e1a.w,  c0a.z, c0a.w, c1a.z, c1a.w,  e1o, c1o);
    win2x2(e0b.x, e0b.y, e1b.x, e1b.y,  c0b.x, c0b.y, c1b.x, c1b.y,  e2o, c2o);
    win2x2(e0b.z, e0b.w, e1b.z, e1b.w,  c0b.z, c0b.w, c1b.z, c1b.w,  e3o, c3o);

    floatx4 eo = { e0o, e1o, e2o, e3o };
    floatx4 co = { c0o * DEVALUE, c1o * DEVALUE, c2o * DEVALUE, c3o * DEVALUE };

    size_t out_base = (size_t)bc * (HOUT * WOUT) + (size_t)ho * WOUT + (size_t)(wo4 * 4);
    __builtin_nontemporal_store(eo, reinterpret_cast<floatx4*>(out_e  + out_base));
    __builtin_nontemporal_store(co, reinterpret_cast<floatx4*>(out_ce + out_base));
}

extern "C" void kernel_launch(void* const* d_in, const int* in_sizes, int n_in,
                              void* d_out, int out_size, void* d_ws, size_t ws_size,
                              hipStream_t stream) {
    // Inputs (setup_inputs order): d [unused], cd [unused], e, ce
    const float* e  = (const float*)d_in[2];
    const float* ce = (const float*)d_in[3];

    const size_t plane_out = (size_t)NPLANES * HOUT * WOUT;  // 10,485,760
    float* out_e  = (float*)d_out;
    float* out_ce = out_e + plane_out;

    // 160 planes * 256 rows * 64 thread-cols = 2,621,440 threads -> 10240 blocks (exact)
    const int total_threads = NPLANES * HOUT * (WOUT / 4);
    const int block = 256;
    const int grid = total_threads / block;  // 10240

    pool_gather_kernel<<<grid, block, 0, stream>>>(e, ce, out_e, out_ce);
}

// Round 5
// 73.222 us; speedup vs baseline: 1.0923x; 1.0155x over previous
//
#include <hip/hip_runtime.h>

// B=8, C=5, D=4 -> planes = 160; H=W=512 -> Hout=Wout=256; K=STRIDE=2; DEVALUE=0.25
#define NPLANES 160
#define HIN 512
#define WIN 512
#define HOUT 256
#define WOUT 256
#define DEVALUE 0.25f

typedef float floatx4 __attribute__((ext_vector_type(4)));

// argmax over one 2x2 window (first-max tie-break order: (r0,c0),(r0,c1),(r1,c0),(r1,c1))
__device__ __forceinline__ void win2x2(float e00, float e01, float e10, float e11,
                                       float c00, float c01, float c10, float c11,
                                       float& eo, float& co)
{
    float v0 = c00 * (1.0f - e00);
    float v1 = c01 * (1.0f - e01);
    float v2 = c10 * (1.0f - e10);
    float v3 = c11 * (1.0f - e11);
    float best = v0; eo = e00; co = c00;
    if (v1 > best) { best = v1; eo = e01; co = c01; }
    if (v2 > best) { best = v2; eo = e10; co = c10; }
    if (v3 > best) { best = v3; eo = e11; co = c11; }
}

// Process one 2x4-output sub-block: input rows r0,r1 (float4 pairs a/b), 8 cols.
__device__ __forceinline__ void row4(const float4& e0a, const float4& e0b,
                                     const float4& e1a, const float4& e1b,
                                     const float4& c0a, const float4& c0b,
                                     const float4& c1a, const float4& c1b,
                                     floatx4& eo, floatx4& co)
{
    float a0, b0, a1, b1, a2, b2, a3, b3;
    win2x2(e0a.x, e0a.y, e1a.x, e1a.y,  c0a.x, c0a.y, c1a.x, c1a.y,  a0, b0);
    win2x2(e0a.z, e0a.w, e1a.z, e1a.w,  c0a.z, c0a.w, c1a.z, c1a.w,  a1, b1);
    win2x2(e0b.x, e0b.y, e1b.x, e1b.y,  c0b.x, c0b.y, c1b.x, c1b.y,  a2, b2);
    win2x2(e0b.z, e0b.w, e1b.z, e1b.w,  c0b.z, c0b.w, c1b.z, c1b.w,  a3, b3);
    eo = (floatx4){ a0, a1, a2, a3 };
    co = (floatx4){ b0 * DEVALUE, b1 * DEVALUE, b2 * DEVALUE, b3 * DEVALUE };
}

// One thread handles a 4-wide x 2-tall block of output pixels
// (8 input cols x 4 input rows; 16 float4 loads, 4 float4 NT stores).
__global__ __launch_bounds__(256) void pool_gather_kernel(
    const float* __restrict__ e,
    const float* __restrict__ ce,
    float* __restrict__ out_e,
    float* __restrict__ out_ce)
{
    int t = blockIdx.x * 256 + threadIdx.x;
    int wo4 = t & 63;          // 64 thread-columns per output row (4 pixels each)
    int ho2 = (t >> 6) & 127;  // output row-pair
    int bc  = t >> 13;         // plane

    size_t in_base = (size_t)bc * (HIN * WIN) + (size_t)(ho2 * 4) * WIN + (size_t)(wo4 * 8);

    const float4* ep = reinterpret_cast<const float4*>(e  + in_base);
    const float4* cp = reinterpret_cast<const float4*>(ce + in_base);
    const int R = WIN / 4;  // row stride in float4s

    // Issue all 16 loads up front (compiler will queue them on vmcnt).
    const float4 e0a = ep[0],       e0b = ep[1];
    const float4 e1a = ep[R],       e1b = ep[R + 1];
    const float4 e2a = ep[2 * R],   e2b = ep[2 * R + 1];
    const float4 e3a = ep[3 * R],   e3b = ep[3 * R + 1];
    const float4 c0a = cp[0],       c0b = cp[1];
    const float4 c1a = cp[R],       c1b = cp[R + 1];
    const float4 c2a = cp[2 * R],   c2b = cp[2 * R + 1];
    const float4 c3a = cp[3 * R],   c3b = cp[3 * R + 1];

    floatx4 eo0, co0, eo1, co1;
    row4(e0a, e0b, e1a, e1b,  c0a, c0b, c1a, c1b,  eo0, co0);
    row4(e2a, e2b, e3a, e3b,  c2a, c2b, c3a, c3b,  eo1, co1);

    size_t out_base = (size_t)bc * (HOUT * WOUT) + (size_t)(ho2 * 2) * WOUT + (size_t)(wo4 * 4);
    __builtin_nontemporal_store(eo0, reinterpret_cast<floatx4*>(out_e  + out_base));
    __builtin_nontemporal_store(co0, reinterpret_cast<floatx4*>(out_ce + out_base));
    __builtin_nontemporal_store(eo1, reinterpret_cast<floatx4*>(out_e  + out_base + WOUT));
    __builtin_nontemporal_store(co1, reinterpret_cast<floatx4*>(out_ce + out_base + WOUT));
}

extern "C" void kernel_launch(void* const* d_in, const int* in_sizes, int n_in,
                              void* d_out, int out_size, void* d_ws, size_t ws_size,
                              hipStream_t stream) {
    // Inputs (setup_inputs order): d [unused], cd [unused], e, ce
    const float* e  = (const float*)d_in[2];
    const float* ce = (const float*)d_in[3];

    const size_t plane_out = (size_t)NPLANES * HOUT * WOUT;  // 10,485,760
    float* out_e  = (float*)d_out;
    float* out_ce = out_e + plane_out;

    // 160 planes * 128 row-pairs * 64 thread-cols = 1,310,720 threads -> 5120 blocks (exact)
    const int total_threads = NPLANES * (HOUT / 2) * (WOUT / 4);
    const int block = 256;
    const int grid = total_threads / block;  // 5120

    pool_gather_kernel<<<grid, block, 0, stream>>>(e, ce, out_e, out_ce);
}